// Round 25
// baseline (32.728 us; speedup 1.0000x reference)
//
#include <hip/hip_runtime.h>

typedef float v2f __attribute__((ext_vector_type(2)));

// Canonical wave64 inclusive prefix-sum (AMD GCN scan sequence).
__device__ __forceinline__ float scan64(float d) {
    d += __int_as_float(__builtin_amdgcn_update_dpp(0, __float_as_int(d), 0x111, 0xF, 0xF, true));
    d += __int_as_float(__builtin_amdgcn_update_dpp(0, __float_as_int(d), 0x112, 0xF, 0xF, true));
    d += __int_as_float(__builtin_amdgcn_update_dpp(0, __float_as_int(d), 0x114, 0xF, 0xF, true));
    d += __int_as_float(__builtin_amdgcn_update_dpp(0, __float_as_int(d), 0x118, 0xF, 0xF, true));
    d += __int_as_float(__builtin_amdgcn_update_dpp(0, __float_as_int(d), 0x142, 0xA, 0xF, true));
    d += __int_as_float(__builtin_amdgcn_update_dpp(0, __float_as_int(d), 0x143, 0xC, 0xF, true));
    return d;
}

__device__ __forceinline__ float rdl63(float v) {
    return __int_as_float(__builtin_amdgcn_readlane(__float_as_int(v), 63));
}

// Round-20 math (256-span, 4 steps/lane, K-collapsed Jacobian, packed float4
// stores). Single change vs r20: stores are SOFTWARE-PIPELINED BY ONE BLOCK.
// Block g's payload is computed into dedicated save-registers and only ISSUED
// at the top of block g+1; the save-regs are reused a full block (~9k cy)
// after issue, so store-retire latency (the hypothesized stall) is hidden.
__global__ __launch_bounds__(64, 4) void ode_wf256x4ds(
    const float* __restrict__ thr,   // B x (N+1)
    const float* __restrict__ DOD,   // B
    const float* __restrict__ Vav,   // B
    const float* __restrict__ C0,    // B
    const float* __restrict__ R0,    // B
    const float* __restrict__ W1,    // 10 x 5
    const float* __restrict__ b1,    // 10
    const float* __restrict__ W2,    // 5 x 10
    const float* __restrict__ b2,    // 5
    float* __restrict__ out,         // B x (N+1) x 2
    int B, int N)
{
    const int j   = threadIdx.x & 63;
    const int row = blockIdx.x;         // 1 row per wave
    if (row >= B) return;

    const float k2  = 2.0f * 1.4426950408889634f;
    const float ln2 = 0.6931471805599453f;
    const float dod = DOD[row], vav = Vav[row];

    v2f bw[5], w0k[5], w3k[5], w4k[5], wa[5], wb[5];
    float c3 = b2[3], c4 = b2[4];
#pragma unroll
    for (int i = 0; i < 5; ++i) {
#pragma unroll
        for (int p = 0; p < 2; ++p) {
            int h = i + 5 * p;
            float a0 = W1[h * 5 + 0];
            float a1 = W1[h * 5 + 1];
            float a2 = W1[h * 5 + 2];
            float a3 = W1[h * 5 + 3];
            float a4 = W1[h * 5 + 4];
            bw[i][p]  = k2 * (b1[h] + a1 * dod + a2 * vav);
            w0k[i][p] = k2 * a0;
            w3k[i][p] = k2 * a3;
            w4k[i][p] = k2 * a4;
            float v3 = W2[30 + h];
            float v4 = W2[40 + h];
            c3 += v3; c4 += v4;
            wa[i][p] = -2.0f * v3;
            wb[i][p] = -2.0f * v4;
        }
    }

    float Y3 = C0[row], Y4 = R0[row];            // exact state entering block
    const float* trp = thr + (size_t)row * (size_t)(N + 1);
    float2* orow = (float2*)(out + (size_t)row * (size_t)(N + 1) * 2);
    const bool alignA = ((row & 1) == 0);        // even rows: index 4j 16B-aligned
    if (!alignA && j == 0) orow[0] = make_float2(Y3, Y4);

    // t buffers: tc = block g (resident), tn = block g+1 (resident)
    float tc[5], tn[5], tbc, tbn;
#pragma unroll
    for (int k = 0; k < 5; ++k) tc[k] = trp[min(4 * j + k, N)];
    tbc = trp[0];
#pragma unroll
    for (int k = 0; k < 5; ++k) tn[k] = trp[min(256 + 4 * j + k, N)];
    tbn = trp[min(256, N)];

    // bootstrap slope F(Y, tb)
    float F3p, F4p;
    {
        v2f Fa = {c3, 0.f}, Fb = {c4, 0.f};
#pragma unroll
        for (int i = 0; i < 5; ++i) {
            v2f x = w3k[i] * Y3 + (w4k[i] * Y4 + (w0k[i] * tbc + bw[i]));
            v2f e; e.x = __builtin_amdgcn_exp2f(x.x); e.y = __builtin_amdgcn_exp2f(x.y);
            v2f A = e + 1.0f;
            v2f s; s.x = __builtin_amdgcn_rcpf(A.x); s.y = __builtin_amdgcn_rcpf(A.y);
            Fa += wa[i] * s;
            Fb += wb[i] * s;
        }
        F3p = Fa.x + Fa.y; F4p = Fb.x + Fb.y;
    }
    float dF3 = 0.f, dF4 = 0.f;

    const int nblk = (N + 255) >> 8;
    const int nSt  = N >> 8;                     // packed-store blocks

    // deferred-store state (issued one block late so retire is hidden)
    float sA0, sA1, sA2, sA3, sB0, sB1, sB2, sB3, sO3, sO4;
    int   sP0 = -1;                              // <0: nothing pending

    for (int g = 0; g < nblk; ++g) {
        const int base = g << 8;

        // ---- issue PREVIOUS block's stores (sources reused only at the ----
        // ---- end of THIS block => ~9k cy of retire cover)              ----
        if (sP0 >= 0) {
            if (alignA) {
                float4* dst = (float4*)(orow + sP0);
                float4 v0 = {sA0, sA1, sA2, sA3};
                float4 v1 = {sB0, sB1, sB2, sB3};
                dst[0] = v0;
                dst[1] = v1;
                if (sP0 + 4 == N) orow[N] = make_float2(sO3, sO4);
            } else {
                float4* dst = (float4*)(orow + sP0 + 1);
                float4 v0 = {sA0, sA1, sA2, sA3};
                float4 v1 = {sB0, sB1, sB2, sB3};
                dst[0] = v0;
                dst[1] = v1;
            }
            sP0 = -1;
        }

        // depth-2 prefetch (block g+2)
        const int pf = base + 512;
        float tf[5], tbf;
#pragma unroll
        for (int k = 0; k < 5; ++k) tf[k] = trp[min(pf + 4 * j + k, N)];
        tbf = trp[min(pf, N)];

        const float h0 = tc[1] - tc[0];          // 0 on clamped lanes
        const float h1 = tc[2] - tc[1];
        const float h2 = tc[3] - tc[2];
        const float h3 = tc[4] - tc[3];

        // 2nd-order predictor at the 4 points
        float z3[4], z4[4];
#pragma unroll
        for (int k = 0; k < 4; ++k) {
            float dt = tc[k] - tbc;
            z3[k] = fmaf(dt, fmaf(0.5f * dt, dF3, F3p), Y3);
            z4[k] = fmaf(dt, fmaf(0.5f * dt, dF4, F4p), Y4);
        }

        // ---- ONE full MLP eval at (z[0], t0); keep s -> Jacobian weights ----
        v2f tq[5];
        float F30, F40;
        {
            v2f Fa = {c3, 0.f}, Fb = {c4, 0.f};
#pragma unroll
            for (int i = 0; i < 5; ++i) {
                v2f x = w3k[i] * z3[0] + (w4k[i] * z4[0] + (w0k[i] * tc[0] + bw[i]));
                v2f e; e.x = __builtin_amdgcn_exp2f(x.x);
                       e.y = __builtin_amdgcn_exp2f(x.y);
                v2f A = e + 1.0f;
                v2f s; s.x = __builtin_amdgcn_rcpf(A.x);
                       s.y = __builtin_amdgcn_rcpf(A.y);
                tq[i] = s;
                Fa += wa[i] * s;
                Fb += wb[i] * s;
            }
            F30 = Fa.x + Fa.y; F40 = Fb.x + Fb.y;
        }
#pragma unroll
        for (int i = 0; i < 5; ++i) tq[i] = tq[i] - tq[i] * tq[i];  // s(1-s)

        // ---- Jacobian collapsed to 6 per-lane scalars (pre-scaled ln2) ----
        float K3a, K4a, Kta, K3b, K4b, Ktb;
        {
            v2f a3 = {0.f,0.f}, a4 = {0.f,0.f}, at = {0.f,0.f};
            v2f b3 = {0.f,0.f}, b4 = {0.f,0.f}, bt = {0.f,0.f};
#pragma unroll
            for (int i = 0; i < 5; ++i) {
                v2f ma = wa[i] * tq[i];
                v2f mb = wb[i] * tq[i];
                a3 += ma * w3k[i]; a4 += ma * w4k[i]; at += ma * w0k[i];
                b3 += mb * w3k[i]; b4 += mb * w4k[i]; bt += mb * w0k[i];
            }
            K3a = ln2 * (a3.x + a3.y); K4a = ln2 * (a4.x + a4.y);
            Kta = ln2 * (at.x + at.y);
            K3b = ln2 * (b3.x + b3.y); K4b = ln2 * (b4.x + b4.y);
            Ktb = ln2 * (bt.x + bt.y);
        }

        // ---- slopes at points 1..3 via J (scalar form) ----
        float F3v[4], F4v[4];
        F3v[0] = F30; F4v[0] = F40;
#pragma unroll
        for (int k = 1; k < 4; ++k) {
            float D3 = z3[k] - z3[0];
            float D4 = z4[k] - z4[0];
            float Dt = tc[k] - tc[0];
            F3v[k] = F30 - fmaf(K3a, D3, fmaf(K4a, D4, Kta * Dt));
            F4v[k] = F40 - fmaf(K3b, D3, fmaf(K4b, D4, Ktb * Dt));
        }

        // ---- sweep 1: combined increment, one scan-pair over 256 steps ----
        float d3 = fmaf(h0, F3v[0], fmaf(h1, F3v[1], fmaf(h2, F3v[2], h3 * F3v[3])));
        float d4 = fmaf(h0, F4v[0], fmaf(h1, F4v[1], fmaf(h2, F4v[2], h3 * F4v[3])));
        float S3 = scan64(d3);
        float S4 = scan64(d4);

        // corrected states in prefix form -> dm
        float dm3, dm4;
        {
            float cb3 = Y3 + (S3 - d3), cb4 = Y4 + (S4 - d4);
            float a1 = h0 * F3v[0];
            float a2 = fmaf(h1, F3v[1], a1);
            float a3 = fmaf(h2, F3v[2], a2);
            float b1_ = h0 * F4v[0];
            float b2_ = fmaf(h1, F4v[1], b1_);
            float b3_ = fmaf(h2, F4v[2], b2_);
            float e0 = cb3 - z3[0];
            float e1 = (cb3 + a1) - z3[1];
            float e2 = (cb3 + a2) - z3[2];
            float e3 = (cb3 + a3) - z3[3];
            dm3 = fmaf(h0, e0, h1 * e1) + fmaf(h2, e2, h3 * e3);
            float f0 = cb4 - z4[0];
            float f1 = (cb4 + b1_) - z4[1];
            float f2 = (cb4 + b2_) - z4[2];
            float f3 = (cb4 + b3_) - z4[3];
            dm4 = fmaf(h0, f0, h1 * f1) + fmaf(h2, f2, h3 * f3);
        }

        // ---- sweep 2 fused through J (scalar), second scan-pair ----
        float d3p = d3 - fmaf(K3a, dm3, K4a * dm4);
        float d4p = d4 - fmaf(K3b, dm3, K4b * dm4);
        float S3p = scan64(d3p);
        float S4p = scan64(d4p);

        // ---- outputs: compute payload into save-regs (stored next block) ----
        float o3 = Y3 + S3p, o4 = Y4 + S4p;               // after step p0+3
        float w23 = fmaf(-h3, F3v[3], o3), w24 = fmaf(-h3, F4v[3], o4); // p0+2
        float w13 = fmaf(-h2, F3v[2], w23), w14 = fmaf(-h2, F4v[2], w24); // p0+1
        float w03 = fmaf(-h1, F3v[1], w13), w04 = fmaf(-h1, F4v[1], w14); // p0
        const int p0 = base + 4 * j;
        if (g < nSt) {
            if (alignA) {
                // indices p0..p0+3 = states after steps p0-1..p0+2
                sA0 = Y3 + (S3p - d3p); sA1 = Y4 + (S4p - d4p); // after p0-1
                sA2 = w03; sA3 = w04;
                sB0 = w13; sB1 = w14; sB2 = w23; sB3 = w24;
            } else {
                // indices p0+1..p0+4 = states after steps p0..p0+3
                sA0 = w03; sA1 = w04; sA2 = w13; sA3 = w14;
                sB0 = w23; sB1 = w24; sB2 = o3;  sB3 = o4;
            }
            sO3 = o3; sO4 = o4;
            sP0 = p0;
        } else {
            // generic guarded tail (immediate scalar stores; not taken for
            // N a multiple of 256)
            if (alignA && j == 0) orow[base] = make_float2(Y3, Y4);
            if (p0 + 3 < N) orow[p0 + 4] = make_float2(o3, o4);
            if (p0 + 2 < N) orow[p0 + 3] = make_float2(w23, w24);
            if (p0 + 1 < N) orow[p0 + 2] = make_float2(w13, w14);
            if (p0 < N)     orow[p0 + 1] = make_float2(w03, w04);
        }

        // ---- carry via readlane; span uses resident tbn ----
        float F3n = rdl63(F3v[3]);
        float F4n = rdl63(F4v[3]);
        Y3 += rdl63(S3p);
        Y4 += rdl63(S4p);
        float span = tbn - tbc;
        float inv = (span > 0.f) ? __builtin_amdgcn_rcpf(span) : 0.f;
        dF3 = (F3n - F3p) * inv;
        dF4 = (F4n - F4p) * inv;
        F3p = F3n; F4p = F4n;

        // rotate t buffers
#pragma unroll
        for (int k = 0; k < 5; ++k) { tc[k] = tn[k]; tn[k] = tf[k]; }
        tbc = tbn; tbn = tbf;
    }

    // ---- epilogue: flush the last block's deferred stores ----
    if (sP0 >= 0) {
        if (alignA) {
            float4* dst = (float4*)(orow + sP0);
            float4 v0 = {sA0, sA1, sA2, sA3};
            float4 v1 = {sB0, sB1, sB2, sB3};
            dst[0] = v0;
            dst[1] = v1;
            if (sP0 + 4 == N) orow[N] = make_float2(sO3, sO4);
        } else {
            float4* dst = (float4*)(orow + sP0 + 1);
            float4 v0 = {sA0, sA1, sA2, sA3};
            float4 v1 = {sB0, sB1, sB2, sB3};
            dst[0] = v0;
            dst[1] = v1;
        }
    }
}

extern "C" void kernel_launch(void* const* d_in, const int* in_sizes, int n_in,
                              void* d_out, int out_size, void* d_ws, size_t ws_size,
                              hipStream_t stream) {
    const float* thr = (const float*)d_in[0];
    const float* DOD = (const float*)d_in[1];
    const float* Vav = (const float*)d_in[2];
    const float* C0  = (const float*)d_in[3];
    const float* R0  = (const float*)d_in[4];
    const float* W1  = (const float*)d_in[5];
    const float* b1  = (const float*)d_in[6];
    const float* W2  = (const float*)d_in[7];
    const float* b2  = (const float*)d_in[8];
    float* out = (float*)d_out;

    int B = in_sizes[1];             // DOD is (1,B)
    int N = in_sizes[0] / B - 1;     // throughput is (B, N+1)

    dim3 block(64);
    dim3 grid(B);                    // 1 row per 64-thread wave
    ode_wf256x4ds<<<grid, block, 0, stream>>>(thr, DOD, Vav, C0, R0,
                                              W1, b1, W2, b2, out, B, N);
}

// Round 26
// 29.434 us; speedup vs baseline: 1.1119x; 1.1119x over previous
//
#include <hip/hip_runtime.h>

typedef float v2f __attribute__((ext_vector_type(2)));

// Canonical wave64 inclusive prefix-sum (AMD GCN scan sequence).
__device__ __forceinline__ float scan64(float d) {
    d += __int_as_float(__builtin_amdgcn_update_dpp(0, __float_as_int(d), 0x111, 0xF, 0xF, true));
    d += __int_as_float(__builtin_amdgcn_update_dpp(0, __float_as_int(d), 0x112, 0xF, 0xF, true));
    d += __int_as_float(__builtin_amdgcn_update_dpp(0, __float_as_int(d), 0x114, 0xF, 0xF, true));
    d += __int_as_float(__builtin_amdgcn_update_dpp(0, __float_as_int(d), 0x118, 0xF, 0xF, true));
    d += __int_as_float(__builtin_amdgcn_update_dpp(0, __float_as_int(d), 0x142, 0xA, 0xF, true));
    d += __int_as_float(__builtin_amdgcn_update_dpp(0, __float_as_int(d), 0x143, 0xC, 0xF, true));
    return d;
}

__device__ __forceinline__ float rdl63(float v) {
    return __int_as_float(__builtin_amdgcn_readlane(__float_as_int(v), 63));
}

// r20 math + r22 LDS double-buffered t-stream (global_load_lds: unsinkable,
// issued a full block before use) + COUNTED vmcnt(2) at block top: drains
// exactly the 5 t-loads (FIFO-oldest), lets the previous block's 2 packed
// stores float until the compiler's own late waitcnt (~7k cy cover). r22's
// vmcnt(0) conflated store-retire with load-wait; this isolates it.
__global__ __launch_bounds__(64, 4) void ode_wf256ldsv2(
    const float* __restrict__ thr,   // B x (N+1)
    const float* __restrict__ DOD,   // B
    const float* __restrict__ Vav,   // B
    const float* __restrict__ C0,    // B
    const float* __restrict__ R0,    // B
    const float* __restrict__ W1,    // 10 x 5
    const float* __restrict__ b1,    // 10
    const float* __restrict__ W2,    // 5 x 10
    const float* __restrict__ b2,    // 5
    float* __restrict__ out,         // B x (N+1) x 2
    int B, int N)
{
    const int j   = threadIdx.x & 63;
    const int row = blockIdx.x;         // 1 row per wave (1-wave workgroup)
    if (row >= B) return;

    __shared__ float tl[2][320];        // double-buffered t: t[base .. base+319]

    const float k2  = 2.0f * 1.4426950408889634f;
    const float ln2 = 0.6931471805599453f;
    const float dod = DOD[row], vav = Vav[row];

    v2f bw[5], w0k[5], w3k[5], w4k[5], wa[5], wb[5];
    float c3 = b2[3], c4 = b2[4];
#pragma unroll
    for (int i = 0; i < 5; ++i) {
#pragma unroll
        for (int p = 0; p < 2; ++p) {
            int h = i + 5 * p;
            float a0 = W1[h * 5 + 0];
            float a1 = W1[h * 5 + 1];
            float a2 = W1[h * 5 + 2];
            float a3 = W1[h * 5 + 3];
            float a4 = W1[h * 5 + 4];
            bw[i][p]  = k2 * (b1[h] + a1 * dod + a2 * vav);
            w0k[i][p] = k2 * a0;
            w3k[i][p] = k2 * a3;
            w4k[i][p] = k2 * a4;
            float v3 = W2[30 + h];
            float v4 = W2[40 + h];
            c3 += v3; c4 += v4;
            wa[i][p] = -2.0f * v3;
            wb[i][p] = -2.0f * v4;
        }
    }

    float Y3 = C0[row], Y4 = R0[row];            // exact state entering block
    const float* trp = thr + (size_t)row * (size_t)(N + 1);
    float2* orow = (float2*)(out + (size_t)row * (size_t)(N + 1) * 2);
    const bool alignA = ((row & 1) == 0);        // even rows: index 4j 16B-aligned
    if (!alignA && j == 0) orow[0] = make_float2(Y3, Y4);

    // prologue: async-load block 0's t window into tl[0], then drain once
#pragma unroll
    for (int i = 0; i < 5; ++i) {
        int idx = min(i * 64 + j, N);
        __builtin_amdgcn_global_load_lds(
            (const __attribute__((address_space(1))) float*)(trp + idx),
            (__attribute__((address_space(3))) float*)&tl[0][i * 64], 4, 0, 0);
    }

    // bootstrap slope F(Y, t[0]) — direct global read for t[0]
    float tb0 = trp[0];
    float F3p, F4p;
    {
        v2f Fa = {c3, 0.f}, Fb = {c4, 0.f};
#pragma unroll
        for (int i = 0; i < 5; ++i) {
            v2f x = w3k[i] * Y3 + (w4k[i] * Y4 + (w0k[i] * tb0 + bw[i]));
            v2f e; e.x = __builtin_amdgcn_exp2f(x.x); e.y = __builtin_amdgcn_exp2f(x.y);
            v2f A = e + 1.0f;
            v2f s; s.x = __builtin_amdgcn_rcpf(A.x); s.y = __builtin_amdgcn_rcpf(A.y);
            Fa += wa[i] * s;
            Fb += wb[i] * s;
        }
        F3p = Fa.x + Fa.y; F4p = Fb.x + Fb.y;
    }
    float dF3 = 0.f, dF4 = 0.f;

    // block-0 loads must be fully landed before the loop's vmcnt(2) discipline
    asm volatile("s_waitcnt vmcnt(0)" ::: "memory");

    const int nblk = (N + 255) >> 8;
    const int nSt  = N >> 8;                     // packed-store blocks
    int cur = 0;

    for (int g = 0; g < nblk; ++g) {
        const int base = g << 8;
        const int nb = base + 256;
        const int nxt = cur ^ 1;

        // counted wait: drain this buffer's 5 loads (FIFO-oldest, issued a
        // block ago -> free); let the previous block's 2 stores float.
        asm volatile("s_waitcnt vmcnt(2)" ::: "memory");

        float tc[5];
#pragma unroll
        for (int k = 0; k < 5; ++k) tc[k] = tl[cur][4 * j + k];
        const float tbc = tl[cur][0];
        const float tbn = tl[cur][256];

        // issue next block's async t-load (cannot be sunk by the compiler)
#pragma unroll
        for (int i = 0; i < 5; ++i) {
            int idx = min(nb + i * 64 + j, N);
            __builtin_amdgcn_global_load_lds(
                (const __attribute__((address_space(1))) float*)(trp + idx),
                (__attribute__((address_space(3))) float*)&tl[nxt][i * 64], 4, 0, 0);
        }

        const float h0 = tc[1] - tc[0];          // 0 on clamped lanes
        const float h1 = tc[2] - tc[1];
        const float h2 = tc[3] - tc[2];
        const float h3 = tc[4] - tc[3];

        // 2nd-order predictor at the 4 points
        float z3[4], z4[4];
#pragma unroll
        for (int k = 0; k < 4; ++k) {
            float dt = tc[k] - tbc;
            z3[k] = fmaf(dt, fmaf(0.5f * dt, dF3, F3p), Y3);
            z4[k] = fmaf(dt, fmaf(0.5f * dt, dF4, F4p), Y4);
        }

        // ---- ONE full MLP eval at (z[0], t0); keep s -> Jacobian weights ----
        v2f tq[5];
        float F30, F40;
        {
            v2f Fa = {c3, 0.f}, Fb = {c4, 0.f};
#pragma unroll
            for (int i = 0; i < 5; ++i) {
                v2f x = w3k[i] * z3[0] + (w4k[i] * z4[0] + (w0k[i] * tc[0] + bw[i]));
                v2f e; e.x = __builtin_amdgcn_exp2f(x.x);
                       e.y = __builtin_amdgcn_exp2f(x.y);
                v2f A = e + 1.0f;
                v2f s; s.x = __builtin_amdgcn_rcpf(A.x);
                       s.y = __builtin_amdgcn_rcpf(A.y);
                tq[i] = s;
                Fa += wa[i] * s;
                Fb += wb[i] * s;
            }
            F30 = Fa.x + Fa.y; F40 = Fb.x + Fb.y;
        }
#pragma unroll
        for (int i = 0; i < 5; ++i) tq[i] = tq[i] - tq[i] * tq[i];  // s(1-s)

        // ---- Jacobian collapsed to 6 per-lane scalars (pre-scaled ln2) ----
        float K3a, K4a, Kta, K3b, K4b, Ktb;
        {
            v2f a3 = {0.f,0.f}, a4 = {0.f,0.f}, at = {0.f,0.f};
            v2f b3 = {0.f,0.f}, b4 = {0.f,0.f}, bt = {0.f,0.f};
#pragma unroll
            for (int i = 0; i < 5; ++i) {
                v2f ma = wa[i] * tq[i];
                v2f mb = wb[i] * tq[i];
                a3 += ma * w3k[i]; a4 += ma * w4k[i]; at += ma * w0k[i];
                b3 += mb * w3k[i]; b4 += mb * w4k[i]; bt += mb * w0k[i];
            }
            K3a = ln2 * (a3.x + a3.y); K4a = ln2 * (a4.x + a4.y);
            Kta = ln2 * (at.x + at.y);
            K3b = ln2 * (b3.x + b3.y); K4b = ln2 * (b4.x + b4.y);
            Ktb = ln2 * (bt.x + bt.y);
        }

        // ---- slopes at points 1..3 via J (scalar form) ----
        float F3v[4], F4v[4];
        F3v[0] = F30; F4v[0] = F40;
#pragma unroll
        for (int k = 1; k < 4; ++k) {
            float D3 = z3[k] - z3[0];
            float D4 = z4[k] - z4[0];
            float Dt = tc[k] - tc[0];
            F3v[k] = F30 - fmaf(K3a, D3, fmaf(K4a, D4, Kta * Dt));
            F4v[k] = F40 - fmaf(K3b, D3, fmaf(K4b, D4, Ktb * Dt));
        }

        // ---- sweep 1: combined increment, one scan-pair over 256 steps ----
        float d3 = fmaf(h0, F3v[0], fmaf(h1, F3v[1], fmaf(h2, F3v[2], h3 * F3v[3])));
        float d4 = fmaf(h0, F4v[0], fmaf(h1, F4v[1], fmaf(h2, F4v[2], h3 * F4v[3])));
        float S3 = scan64(d3);
        float S4 = scan64(d4);

        // corrected states in prefix form -> dm
        float dm3, dm4;
        {
            float cb3 = Y3 + (S3 - d3), cb4 = Y4 + (S4 - d4);
            float a1 = h0 * F3v[0];
            float a2 = fmaf(h1, F3v[1], a1);
            float a3 = fmaf(h2, F3v[2], a2);
            float b1_ = h0 * F4v[0];
            float b2_ = fmaf(h1, F4v[1], b1_);
            float b3_ = fmaf(h2, F4v[2], b2_);
            float e0 = cb3 - z3[0];
            float e1 = (cb3 + a1) - z3[1];
            float e2 = (cb3 + a2) - z3[2];
            float e3 = (cb3 + a3) - z3[3];
            dm3 = fmaf(h0, e0, h1 * e1) + fmaf(h2, e2, h3 * e3);
            float f0 = cb4 - z4[0];
            float f1 = (cb4 + b1_) - z4[1];
            float f2 = (cb4 + b2_) - z4[2];
            float f3 = (cb4 + b3_) - z4[3];
            dm4 = fmaf(h0, f0, h1 * f1) + fmaf(h2, f2, h3 * f3);
        }

        // ---- sweep 2 fused through J (scalar), second scan-pair ----
        float d3p = d3 - fmaf(K3a, dm3, K4a * dm4);
        float d4p = d4 - fmaf(K3b, dm3, K4b * dm4);
        float S3p = scan64(d3p);
        float S4p = scan64(d4p);

        // ---- outputs: packed 16B-aligned float4 stores ----
        float o3 = Y3 + S3p, o4 = Y4 + S4p;               // after step p0+3
        float w23 = fmaf(-h3, F3v[3], o3), w24 = fmaf(-h3, F4v[3], o4); // p0+2
        float w13 = fmaf(-h2, F3v[2], w23), w14 = fmaf(-h2, F4v[2], w24); // p0+1
        float w03 = fmaf(-h1, F3v[1], w13), w04 = fmaf(-h1, F4v[1], w14); // p0
        const int p0 = base + 4 * j;
        if (g < nSt) {
            if (alignA) {
                float b3 = Y3 + (S3p - d3p), b4 = Y4 + (S4p - d4p); // after p0-1
                float4* dst = (float4*)(orow + p0);
                float4 v0 = {b3, b4, w03, w04};
                float4 v1 = {w13, w14, w23, w24};
                dst[0] = v0;
                dst[1] = v1;
                if (p0 + 4 == N) orow[N] = make_float2(o3, o4);
            } else {
                float4* dst = (float4*)(orow + p0 + 1);
                float4 v0 = {w03, w04, w13, w14};
                float4 v1 = {w23, w24, o3, o4};
                dst[0] = v0;
                dst[1] = v1;
            }
        } else {
            if (alignA && j == 0) orow[base] = make_float2(Y3, Y4);
            if (p0 + 3 < N) orow[p0 + 4] = make_float2(o3, o4);
            if (p0 + 2 < N) orow[p0 + 3] = make_float2(w23, w24);
            if (p0 + 1 < N) orow[p0 + 2] = make_float2(w13, w14);
            if (p0 < N)     orow[p0 + 1] = make_float2(w03, w04);
        }

        // ---- carry via readlane; span uses this buffer's t[base+256] ----
        float F3n = rdl63(F3v[3]);
        float F4n = rdl63(F4v[3]);
        Y3 += rdl63(S3p);
        Y4 += rdl63(S4p);
        float span = tbn - tbc;
        float inv = (span > 0.f) ? __builtin_amdgcn_rcpf(span) : 0.f;
        dF3 = (F3n - F3p) * inv;
        dF4 = (F4n - F4p) * inv;
        F3p = F3n; F4p = F4n;

        cur = nxt;
    }
}

extern "C" void kernel_launch(void* const* d_in, const int* in_sizes, int n_in,
                              void* d_out, int out_size, void* d_ws, size_t ws_size,
                              hipStream_t stream) {
    const float* thr = (const float*)d_in[0];
    const float* DOD = (const float*)d_in[1];
    const float* Vav = (const float*)d_in[2];
    const float* C0  = (const float*)d_in[3];
    const float* R0  = (const float*)d_in[4];
    const float* W1  = (const float*)d_in[5];
    const float* b1  = (const float*)d_in[6];
    const float* W2  = (const float*)d_in[7];
    const float* b2  = (const float*)d_in[8];
    float* out = (float*)d_out;

    int B = in_sizes[1];             // DOD is (1,B)
    int N = in_sizes[0] / B - 1;     // throughput is (B, N+1)

    dim3 block(64);
    dim3 grid(B);                    // 1 row per 64-thread wave
    ode_wf256ldsv2<<<grid, block, 0, stream>>>(thr, DOD, Vav, C0, R0,
                                               W1, b1, W2, b2, out, B, N);
}